// Round 5
// baseline (116.101 us; speedup 1.0000x reference)
//
#include <hip/hip_runtime.h>
#include <stdint.h>

#define NPIX 9216   // 96*96
#define NIMG 32
#define STRIP 1152  // NPIX / 8

// ---------- JAX threefry2x32 (20 rounds), bit-exact (verified rounds 1-12) ----------
__device__ __forceinline__ uint32_t rotl32(uint32_t x, int d){ return (x<<d)|(x>>(32-d)); }

__device__ __forceinline__ void threefry(uint32_t k0, uint32_t k1, uint32_t x0, uint32_t x1,
                                         uint32_t &o0, uint32_t &o1){
  uint32_t ks2 = k0 ^ k1 ^ 0x1BD11BDAu;
  x0 += k0; x1 += k1;
  x0+=x1; x1=rotl32(x1,13); x1^=x0;
  x0+=x1; x1=rotl32(x1,15); x1^=x0;
  x0+=x1; x1=rotl32(x1,26); x1^=x0;
  x0+=x1; x1=rotl32(x1,6);  x1^=x0;
  x0+=k1; x1+=ks2+1u;
  x0+=x1; x1=rotl32(x1,17); x1^=x0;
  x0+=x1; x1=rotl32(x1,29); x1^=x0;
  x0+=x1; x1=rotl32(x1,16); x1^=x0;
  x0+=x1; x1=rotl32(x1,24); x1^=x0;
  x0+=ks2; x1+=k0+2u;
  x0+=x1; x1=rotl32(x1,13); x1^=x0;
  x0+=x1; x1=rotl32(x1,15); x1^=x0;
  x0+=x1; x1=rotl32(x1,26); x1^=x0;
  x0+=x1; x1=rotl32(x1,6);  x1^=x0;
  x0+=k0; x1+=k1+3u;
  x0+=x1; x1=rotl32(x1,17); x1^=x0;
  x0+=x1; x1=rotl32(x1,29); x1^=x0;
  x0+=x1; x1=rotl32(x1,16); x1^=x0;
  x0+=x1; x1=rotl32(x1,24); x1^=x0;
  x0+=k1; x1+=ks2+4u;
  x0+=x1; x1=rotl32(x1,13); x1^=x0;
  x0+=x1; x1=rotl32(x1,15); x1^=x0;
  x0+=x1; x1=rotl32(x1,26); x1^=x0;
  x0+=x1; x1=rotl32(x1,6);  x1^=x0;
  x0+=ks2; x1+=k0+5u;
  o0=x0; o1=x1;
}

__device__ __forceinline__ float clip01_div255(float x){
  return fminf(fmaxf(x/255.0f, 0.0f), 1.0f);
}

// ---------- K1: 256 blocks = img x 8 strips (FULL machine width).
// Per block: redundant image channel-max (8 blocks/img share L2; fmax fold exactly
// associative -> bit-identical, empirically confirmed rounds 1/3/4), then score own
// strip (1 threefry/px, own-class key -- R3/R4 verified), write vv|fg to vvG and
// per-block hist partials (non-atomic global: every slot written -> poison-safe).
__global__ __launch_bounds__(256) void kscore(const float* __restrict__ in,
                                              uint32_t* __restrict__ vvG,       // [32][9216]
                                              int* __restrict__ histPart){      // [32][8][258]
#pragma clang fp contract(off)
  int b   = blockIdx.x;
  int img = b >> 3, sub = b & 7;
  int tid = threadIdx.x;

  __shared__ int   hist[258];      // cls*129 + bin
  __shared__ float wred[3][4];
  __shared__ float cmaxL[3];

  for(int i=tid;i<258;i+=256) hist[i]=0;

  const float* p = in + (size_t)img*NPIX*3;

  // ---- image channel max (redundant per block; L2-served). 6912 float4 / 256 thr.
  // Channel rotation per float4 (verified round 1): elems of float4 #i4 have
  // channels (i4%3, +1, +2, i4%3).
  {
    const float4* ip4 = (const float4*)p;
    float m0=0.f, m1=0.f, m2=0.f;
    for(int k=0;k<27;k++){
      int i4 = k*256 + tid;
      float4 v = ip4[i4];
      float e0=clip01_div255(v.x), e1=clip01_div255(v.y),
            e2=clip01_div255(v.z), e3=clip01_div255(v.w);
      int b3 = i4 % 3;
      float cb = fmaxf(e0,e3);
      m0 = fmaxf(m0, b3==0 ? cb : (b3==1 ? e2 : e1));
      m1 = fmaxf(m1, b3==0 ? e1 : (b3==1 ? cb : e2));
      m2 = fmaxf(m2, b3==0 ? e2 : (b3==1 ? e1 : cb));
    }
    for(int off=32; off>0; off>>=1){
      m0 = fmaxf(m0, __shfl_down(m0,off));
      m1 = fmaxf(m1, __shfl_down(m1,off));
      m2 = fmaxf(m2, __shfl_down(m2,off));
    }
    int lane = tid & 63, wv = tid >> 6;
    if(lane==0){ wred[0][wv]=m0; wred[1][wv]=m1; wred[2][wv]=m2; }
  }
  __syncthreads();
  if(tid<3) cmaxL[tid] = fmaxf(fmaxf(wred[tid][0],wred[tid][1]),
                               fmaxf(wred[tid][2],wred[tid][3]));
  __syncthreads();
  float c0=cmaxL[0], c1=cmaxL[1], c2=cmaxL[2];

  // ---- partitionable threefry keys (bit-exact, verbatim)
  uint32_t ik0, ik1; threefry(0u, 42u, 0u, (uint32_t)img, ik0, ik1);
  uint32_t sf0, sf1; threefry(ik0, ik1, 0u, 0u, sf0, sf1);   // cls=0 (fg)
  uint32_t sb0, sb1; threefry(ik0, ik1, 0u, 1u, sb0, sb1);   // cls=1 (bg)

  // ---- score own strip from registers (math verbatim R4; 1 threefry/px)
  uint32_t* vstrip = vvG + (size_t)img*NPIX + (size_t)sub*STRIP;
  const float4* sp4 = (const float4*)(p + (size_t)sub*STRIP*3);
  auto score_px = [&](int pxl, float pa, float pb, float pc){
    float a  = clip01_div255(pa)/c0;
    float bb = clip01_div255(pb)/c1;
    float c  = clip01_div255(pc)/c2;
    bool fg = (a>0.f && a<0.6f) || (bb>0.f && bb<0.6f) || (c>0.f && c<0.6f);
    uint32_t k0 = fg ? sf0 : sb0, k1 = fg ? sf1 : sb1;
    uint32_t gi = (uint32_t)(sub*STRIP + pxl);          // image-local index
    uint32_t r1, r2; threefry(k0, k1, 0u, gi, r1, r2);
    uint32_t vv = ((r1 ^ r2) >> 9) + 1u;                // monotone in uniform
    vstrip[pxl] = vv | (fg ? 0x80000000u : 0u);
    atomicAdd(&hist[(fg?0:129) + (int)(vv>>16)], 1);
  };
#pragma unroll
  for(int w=0;w<2;w++){
    int g = w*256 + tid;                                 // 288 groups of 4 px
    if(g < 288){
      float4 v0 = sp4[3*g+0], v1 = sp4[3*g+1], v2 = sp4[3*g+2];
      int pb = g*4;
      score_px(pb+0, v0.x, v0.y, v0.z);
      score_px(pb+1, v0.w, v1.x, v1.y);
      score_px(pb+2, v1.z, v1.w, v2.x);
      score_px(pb+3, v2.y, v2.z, v2.w);
    }
  }
  __syncthreads();
  for(int i=tid;i<258;i+=256) histPart[(size_t)b*258 + i] = hist[i];
}

// ---------- K2: 32 blocks x 1024: fold hist partials -> bbin -> compact -> rank ->
// stats (every phase verbatim round-4 kprep, which passed bit-identical). Isolates
// the narrow per-image tail into its own dispatch.
__global__ __launch_bounds__(1024) void kfin(const float* __restrict__ in,
                                             const uint32_t* __restrict__ vvG,
                                             const int* __restrict__ histPart,
                                             float* __restrict__ ts2g,      // [32][600]
                                             float* __restrict__ meanstd){  // [32][10]
#pragma clang fp contract(off)
  int img = blockIdx.x;
  int tid = threadIdx.x;

  __shared__ int      hist2[258];         // cls*129 + bin
  __shared__ uint64_t cand[2][1024];
  __shared__ int      ncA[2], bbinL[2];
  __shared__ int      tIdx[100];
  __shared__ float    feat[100][5];
  __shared__ float    mv[5], sv[5];

  if(tid<2) ncA[tid]=0;
  if(tid<258){
    int s=0;
#pragma unroll
    for(int s8=0;s8<8;s8++) s += histPart[((size_t)img*8+s8)*258 + tid];
    hist2[tid]=s;
  }
  __syncthreads();

  // ---- bbin per class (verified wave scan; wave 0 -> fg, wave 1 -> bg)
  if(tid<128){
    int cls = tid>>6, l = tid&63;
    int h0 = hist2[cls*129 + 2*l];
    int h1 = hist2[cls*129 + 2*l+1];
    int h128 = hist2[cls*129 + 128];
    int S = h0 + h1;
    for(int off=1; off<64; off<<=1){
      int o = __shfl_down(S, off);
      if(l + off < 64) S += o;
    }
    int ss0 = S + h128;
    int ss1 = S - h0 + h128;
    int cd = -1;
    if(ss0 >= 50) cd = 2*l;
    if(ss1 >= 50) cd = 2*l+1;
    if(l==63 && h128 >= 50) cd = 128;
    for(int off=32; off>0; off>>=1){
      int o = __shfl_down(cd, off);
      cd = o > cd ? o : cd;
    }
    if(l==0) bbinL[cls] = cd;
  }
  __syncthreads();

  // ---- compact both classes in one sweep of vvG (semantics verbatim R4)
  const uint32_t* vp = vvG + (size_t)img*NPIX;
  {
    int bb0 = bbinL[0], bb1 = bbinL[1];
    for(int k=0;k<9;k++){
      int px = k*1024 + tid;
      uint32_t w = vp[px];
      int cls = (w & 0x80000000u) ? 0 : 1;
      uint32_t vv = w & 0x7FFFFFFFu;
      int bb = cls ? bb1 : bb0;
      if((int)(vv>>16) >= bb){
        int pos = atomicAdd(&ncA[cls],1);
        if(pos < 1024)
          cand[cls][pos] = ((uint64_t)vv << 14) | (uint64_t)(16383 - px);
      }
    }
  }
  __syncthreads();

  // ---- rank: half-block per class (chunked early-exit, exact for r<50; verbatim)
  {
    int cls = (tid >= 512);
    int lt  = tid & 511;
    int m = ncA[cls]; if(m > 1024) m = 1024;
    const uint64_t* C = cand[cls];
    for(int c=lt; c<m; c+=512){
      uint64_t kk = C[c];
      int r = 0, j = 0;
      while(j < m){
        int je = j+64 < m ? j+64 : m;
        for(; j<je; j++) r += (C[j] > kk);
        if(r >= 50) break;
      }
      if(r < 50) tIdx[cls*50 + r] = 16383 - (int)(kk & 16383u);
    }
  }
  __syncthreads();

  // ---- <50-valid fallback (verbatim semantics; block-uniform branches)
  for(int cls=0; cls<2; cls++){
    if(bbinL[cls] == -1){
      uint32_t want = (cls==0) ? 0x80000000u : 0u;
      if(tid==0){
        int m = ncA[cls];                    // bbin==-1 -> m = class count < 50
        int need = 50 - m, r = m;
        for(int px=0; px<NPIX && need>0; px++){
          if((vp[px] & 0x80000000u) != want){ tIdx[cls*50 + r] = px; r++; need--; }
        }
      }
      __syncthreads();
    }
  }

  // ---- train features + stats (verbatim: identical summation order)
  if(tid<100){
    int pp = tIdx[tid];
    int i=pp/96, j=pp-i*96;
    const float* px = in + ((size_t)img*NPIX + pp)*3;
    for(int c=0;c<3;c++){
      float ip=clip01_div255(px[c]);
      feat[tid][c]=ip/255.0f;
    }
    feat[tid][3]=((float)i/96.0f)*100.0f;
    feat[tid][4]=((float)j/96.0f)*100.0f;
  }
  __syncthreads();
  if(tid<5){
    float s=0.f;
    for(int r=0;r<100;r++) s=s+feat[r][tid];
    float mu=s/100.0f; mv[tid]=mu;
    float v=0.f;
    for(int r=0;r<100;r++){ float d=feat[r][tid]-mu; float q=d*d; v=v+q; }
    sv[tid]=sqrtf(v/100.0f);
  }
  __syncthreads();
  // pair-interleaved layout: f_k of row r at [pair*12 + 2k + (r&1)], pair=r>>1
  if(tid<100){
    float r0=(feat[tid][0]-mv[0])/sv[0];
    float r1=(feat[tid][1]-mv[1])/sv[1];
    float r2=(feat[tid][2]-mv[2])/sv[2];
    float r3=(feat[tid][3]-mv[3])/sv[3];
    float r4=(feat[tid][4]-mv[4])/sv[4];
    float* dst = ts2g + img*600 + (tid>>1)*12 + (tid&1);
    dst[0]=r0; dst[2]=r1; dst[4]=r2; dst[6]=r3; dst[8]=r4;
  }
  if(tid<5)       meanstd[img*10+tid]=mv[tid];
  else if(tid<10) meanstd[img*10+tid]=sv[tid-5];
}

// ---------- K3: 1152 blocks: 5-NN, packed-pair min/max insertion networks
// (verbatim; passed rounds 0/3/4) ----
__global__ __launch_bounds__(256) void kknn(const float* __restrict__ in,
                                            const float* __restrict__ ts2g,
                                            const float* __restrict__ meanstd,
                                            float* __restrict__ out){
#pragma clang fp contract(off)
  int b     = blockIdx.x;
  int img   = b / 36;
  int chunk = b % 36;
  int tid   = threadIdx.x;

  __shared__ float    mv[5], sv[5];
  __shared__ __attribute__((aligned(16))) float ts2[600];  // pair-interleaved rows
  __shared__ __attribute__((aligned(16))) float pix[768];

  if(tid<150) ((float4*)ts2)[tid] = ((const float4*)(ts2g + img*600))[tid];
  if(tid>=192 && tid<197) mv[tid-192]=meanstd[img*10+(tid-192)];
  if(tid>=224 && tid<229) sv[tid-224]=meanstd[img*10+5+(tid-224)];
  {
    const float4* cb4 = (const float4*)(in + ((size_t)img*NPIX + (size_t)chunk*256)*3);
    if(tid<192) ((float4*)pix)[tid] = cb4[tid];
  }
  __syncthreads();

  // test feature for own pixel (bit-identical math)
  int p = chunk*256+tid;
  int i=p/96, j=p-i*96;
  float ip0=clip01_div255(pix[tid*3+0]);
  float ip1=clip01_div255(pix[tid*3+1]);
  float ip2=clip01_div255(pix[tid*3+2]);
  float t0,t1,t2,t3,t4;
  {
    float f0=ip0/255.0f, f1=ip1/255.0f, f2=ip2/255.0f;
    float f3=((float)i/96.0f)*100.0f, f4=((float)j/96.0f)*100.0f;
    t0=(f0-mv[0])/sv[0]; t1=(f1-mv[1])/sv[1]; t2=(f2-mv[2])/sv[2];
    t3=(f3-mv[3])/sv[3]; t4=(f4-mv[4])/sv[4];
  }

  // fg pairs 0..24 (rows 0..49): packed top-2 via min/max insertion network.
  float a0x=1e30f,a0y=1e30f, a1x=1e30f,a1y=1e30f;
#pragma unroll 5
  for(int pr=0;pr<25;pr++){
    const float* tp = &ts2[pr*12];
    float4 qA = *(const float4*)(tp);    // f0(x,y) f1(x,y)
    float4 qB = *(const float4*)(tp+4);  // f2(x,y) f3(x,y)
    float2 qC = *(const float2*)(tp+8);  // f4(x,y)
    float sx, sy;
    { float dx=t0-qA.x, dy=t0-qA.y; sx=dx*dx; sy=dy*dy; }
    { float dx=t1-qA.z, dy=t1-qA.w; float wx=dx*dx, wy=dy*dy; sx=sx+wx; sy=sy+wy; }
    { float dx=t2-qB.x, dy=t2-qB.y; float wx=dx*dx, wy=dy*dy; sx=sx+wx; sy=sy+wy; }
    { float dx=t3-qB.z, dy=t3-qB.w; float wx=dx*dx, wy=dy*dy; sx=sx+wx; sy=sy+wy; }
    { float dx=t4-qC.x, dy=t4-qC.y; float wx=dx*dx, wy=dy*dy; sx=sx+wx; sy=sy+wy; }
    float tx=fmaxf(a0x,sx), ty=fmaxf(a0y,sy);
    a0x=fminf(a0x,sx);      a0y=fminf(a0y,sy);
    a1x=fminf(a1x,tx);      a1y=fminf(a1y,ty);
  }
  // exact 2nd-smallest of union of the two sorted pairs (bitonic split)
  float a1 = fmaxf(fminf(a0x,a1y), fminf(a1x,a0y));

  // bg pairs 25..49 (rows 50..99): packed top-4 insertion network
  float b0x=1e30f,b0y=1e30f, b1x=1e30f,b1y=1e30f;
  float b2x=1e30f,b2y=1e30f, b3x=1e30f,b3y=1e30f;
#pragma unroll 5
  for(int pr=25;pr<50;pr++){
    const float* tp = &ts2[pr*12];
    float4 qA = *(const float4*)(tp);
    float4 qB = *(const float4*)(tp+4);
    float2 qC = *(const float2*)(tp+8);
    float sx, sy;
    { float dx=t0-qA.x, dy=t0-qA.y; sx=dx*dx; sy=dy*dy; }
    { float dx=t1-qA.z, dy=t1-qA.w; float wx=dx*dx, wy=dy*dy; sx=sx+wx; sy=sy+wy; }
    { float dx=t2-qB.x, dy=t2-qB.y; float wx=dx*dx, wy=dy*dy; sx=sx+wx; sy=sy+wy; }
    { float dx=t3-qB.z, dy=t3-qB.w; float wx=dx*dx, wy=dy*dy; sx=sx+wx; sy=sy+wy; }
    { float dx=t4-qC.x, dy=t4-qC.y; float wx=dx*dx, wy=dy*dy; sx=sx+wx; sy=sy+wy; }
    float u0x=fmaxf(b0x,sx), u0y=fmaxf(b0y,sy);
    b0x=fminf(b0x,sx);       b0y=fminf(b0y,sy);
    float u1x=fmaxf(b1x,u0x), u1y=fmaxf(b1y,u0y);
    b1x=fminf(b1x,u0x);       b1y=fminf(b1y,u0y);
    float u2x=fmaxf(b2x,u1x), u2y=fmaxf(b2y,u1y);
    b2x=fminf(b2x,u1x);       b2y=fminf(b2y,u1y);
    b3x=fminf(b3x,u2x);       b3y=fminf(b3y,u2y);
  }
  // exact 4th-smallest of union of two sorted quads (bitonic lower-half merge)
  float l0=fminf(b0x,b3y), l1=fminf(b1x,b2y), l2=fminf(b2x,b1y), l3=fminf(b3x,b0y);
  float b3 = fmaxf(fmaxf(l0,l1), fmaxf(l2,l3));

  // seg <=> 2nd-smallest fg sqrt-dist <= 4th-smallest bg sqrt-dist (fg wins ties)
  bool seg = sqrtf(a1) <= sqrtf(b3);
  __syncthreads();                       // pix reuse fence
  pix[tid*3+0]=seg?ip0:0.f;
  pix[tid*3+1]=seg?ip1:0.f;
  pix[tid*3+2]=seg?ip2:0.f;
  __syncthreads();
  float4* ob4 = (float4*)(out + ((size_t)img*NPIX + (size_t)chunk*256)*3);
  if(tid<192) ob4[tid] = ((float4*)pix)[tid];
}

extern "C" void kernel_launch(void* const* d_in, const int* in_sizes, int n_in,
                              void* d_out, int out_size, void* d_ws, size_t ws_size,
                              hipStream_t stream) {
  const float* in = (const float*)d_in[0];
  float* out = (float*)d_out;
  uint32_t* vvG     = (uint32_t*)d_ws;                          // 1,179,648 B
  int*      histPart= (int*)((char*)d_ws + 1179648);            //   264,192 B
  float*    ts2g    = (float*)((char*)d_ws + 1443840);          //    76,800 B
  float*    meanstd = (float*)((char*)d_ws + 1520640);          //     1,280 B

  kscore<<<256,  256,  0, stream>>>(in, vvG, histPart);
  kfin  <<<32,   1024, 0, stream>>>(in, vvG, histPart, ts2g, meanstd);
  kknn  <<<1152, 256,  0, stream>>>(in, ts2g, meanstd, out);
}

// Round 6
// 103.282 us; speedup vs baseline: 1.1241x; 1.1241x over previous
//
#include <hip/hip_runtime.h>
#include <stdint.h>

#define NPIX 9216   // 96*96
#define NIMG 32
#define STRIP 1152  // NPIX / 8 strips

// ---------- JAX threefry2x32 (20 rounds), bit-exact (verified rounds 1-12) ----------
__device__ __forceinline__ uint32_t rotl32(uint32_t x, int d){ return (x<<d)|(x>>(32-d)); }

__device__ __forceinline__ void threefry(uint32_t k0, uint32_t k1, uint32_t x0, uint32_t x1,
                                         uint32_t &o0, uint32_t &o1){
  uint32_t ks2 = k0 ^ k1 ^ 0x1BD11BDAu;
  x0 += k0; x1 += k1;
  x0+=x1; x1=rotl32(x1,13); x1^=x0;
  x0+=x1; x1=rotl32(x1,15); x1^=x0;
  x0+=x1; x1=rotl32(x1,26); x1^=x0;
  x0+=x1; x1=rotl32(x1,6);  x1^=x0;
  x0+=k1; x1+=ks2+1u;
  x0+=x1; x1=rotl32(x1,17); x1^=x0;
  x0+=x1; x1=rotl32(x1,29); x1^=x0;
  x0+=x1; x1=rotl32(x1,16); x1^=x0;
  x0+=x1; x1=rotl32(x1,24); x1^=x0;
  x0+=ks2; x1+=k0+2u;
  x0+=x1; x1=rotl32(x1,13); x1^=x0;
  x0+=x1; x1=rotl32(x1,15); x1^=x0;
  x0+=x1; x1=rotl32(x1,26); x1^=x0;
  x0+=x1; x1=rotl32(x1,6);  x1^=x0;
  x0+=k0; x1+=k1+3u;
  x0+=x1; x1=rotl32(x1,17); x1^=x0;
  x0+=x1; x1=rotl32(x1,29); x1^=x0;
  x0+=x1; x1=rotl32(x1,16); x1^=x0;
  x0+=x1; x1=rotl32(x1,24); x1^=x0;
  x0+=k1; x1+=ks2+4u;
  x0+=x1; x1=rotl32(x1,13); x1^=x0;
  x0+=x1; x1=rotl32(x1,15); x1^=x0;
  x0+=x1; x1=rotl32(x1,26); x1^=x0;
  x0+=x1; x1=rotl32(x1,6);  x1^=x0;
  x0+=ks2; x1+=k0+5u;
  o0=x0; o1=x1;
}

__device__ __forceinline__ float clip01_div255(float x){
  return fminf(fmaxf(x/255.0f, 0.0f), 1.0f);
}

// ---------- K0: partial channel max, 6 blocks/image (verbatim R0 baseline) -----
__global__ __launch_bounds__(256) void kmax(const float* __restrict__ in,
                                            float* __restrict__ maxpart){
  int img  = blockIdx.x / 6;
  int part = blockIdx.x % 6;
  int tid  = threadIdx.x;
  const float* base = in + (size_t)img*NPIX*3 + (size_t)part*1536*3;
  float m0=0.f, m1=0.f, m2=0.f;
#pragma unroll
  for(int k=0;k<18;k++){
    int g = k*256 + tid;
    float v = clip01_div255(base[g]);
    int c = g % 3;
    m0 = (c==0) ? fmaxf(m0,v) : m0;
    m1 = (c==1) ? fmaxf(m1,v) : m1;
    m2 = (c==2) ? fmaxf(m2,v) : m2;
  }
  for(int off=32; off>0; off>>=1){
    m0 = fmaxf(m0, __shfl_down(m0,off));
    m1 = fmaxf(m1, __shfl_down(m1,off));
    m2 = fmaxf(m2, __shfl_down(m2,off));
  }
  __shared__ float r[3][4];
  int lane = tid & 63, wv = tid >> 6;
  if(lane==0){ r[0][wv]=m0; r[1][wv]=m1; r[2][wv]=m2; }
  __syncthreads();
  if(tid==0){
    maxpart[blockIdx.x*3+0]=fmaxf(fmaxf(r[0][0],r[0][1]),fmaxf(r[0][2],r[0][3]));
    maxpart[blockIdx.x*3+1]=fmaxf(fmaxf(r[1][0],r[1][1]),fmaxf(r[1][2],r[1][3]));
    maxpart[blockIdx.x*3+2]=fmaxf(fmaxf(r[2][0],r[2][1]),fmaxf(r[2][2],r[2][3]));
  }
}

// ---------- K1: 256 blocks = img x 8 strips. ONE threefry per pixel (own-class
// key; R3/R4/R5-verified equivalence) producing BOTH classes' strip-top-50 lists.
// Halves R0-kscore's threefry work + staging while emitting a bit-identical
// key50g: valid keys vv>=1 in own-class list; when a class has <50 in-strip
// (bbin==-1), other-class pixels join as vv=0 fillers whose keys (16383-gi)
// sort after all valid and by ascending index -- exactly R0's invalid-key
// semantics, so the merged global top-50 is unchanged.
__global__ __launch_bounds__(256) void kscore(const float* __restrict__ in,
                                              const float* __restrict__ maxpart,
                                              unsigned long long* __restrict__ key50g){
#pragma clang fp contract(off)
  int b   = blockIdx.x;                 // img*8 + sub
  int img = b >> 3, sub = b & 7;
  int tid = threadIdx.x;

  __shared__ __attribute__((aligned(16))) float pixL[3456];  // strip pixels
  __shared__ uint32_t vvL[STRIP];                            // vv | (fg<<31)
  __shared__ uint64_t cand[2][STRIP];
  __shared__ int hist[258];                                  // cls*129 + bin
  __shared__ int ncA[2], bbinL[2];

  for(int i=tid;i<258;i+=256) hist[i]=0;
  if(tid<2) ncA[tid]=0;

  const float* p = in + (size_t)img*NPIX*3;

  // stage own strip (864 float4, coalesced) -- verbatim R0
  const float4* sp4 = (const float4*)(p + (size_t)sub*STRIP*3);
  float4* pixL4 = (float4*)pixL;
  for(int k=0;k<4;k++){ int i4=k*256+tid; if(i4<864) pixL4[i4]=sp4[i4]; }

  // fold 6 partial maxes (uniform scalar loads; fmax exactly associative) -- verbatim
  float c0=0.f,c1=0.f,c2=0.f;
#pragma unroll
  for(int s=0;s<6;s++){
    c0=fmaxf(c0, maxpart[(img*6+s)*3+0]);
    c1=fmaxf(c1, maxpart[(img*6+s)*3+1]);
    c2=fmaxf(c2, maxpart[(img*6+s)*3+2]);
  }

  // partitionable threefry keys (bit-exact, verbatim derivation)
  uint32_t ik0, ik1; threefry(0u, 42u, 0u, (uint32_t)img, ik0, ik1);
  uint32_t sf0, sf1; threefry(ik0, ik1, 0u, 0u, sf0, sf1);   // cls=0 (fg)
  uint32_t sb0, sb1; threefry(ik0, ik1, 0u, 1u, sb0, sb1);   // cls=1 (bg)
  __syncthreads();

  // score: ONE threefry per pixel with its own class's key (verified R3/R4/R5);
  // dual per-class histogram (every pixel valid for exactly its own class)
  for(int r=0;r<5;r++){
    int pi = tid + r*256;
    if(pi<STRIP){
      float a  = clip01_div255(pixL[pi*3+0])/c0;
      float bb = clip01_div255(pixL[pi*3+1])/c1;
      float c  = clip01_div255(pixL[pi*3+2])/c2;
      bool fg = (a>0.f && a<0.6f) || (bb>0.f && bb<0.6f) || (c>0.f && c<0.6f);
      uint32_t k0 = fg ? sf0 : sb0, k1 = fg ? sf1 : sb1;
      uint32_t gi = (uint32_t)(sub*STRIP + pi);
      uint32_t r1,r2; threefry(k0, k1, 0u, gi, r1, r2);
      uint32_t vv = ((r1 ^ r2) >> 9) + 1u;    // monotone in uniform; >=1 always
      vvL[pi] = vv | (fg ? 0x80000000u : 0u);
      atomicAdd(&hist[(fg?0:129) + (int)(vv>>16)], 1);
    }
  }
  __syncthreads();

  // bbin per class = largest bin with suffix-count >= 50 (verified wave scan;
  // wave 0 -> fg/cls0, wave 1 -> bg/cls1)
  if(tid < 128){
    int cls = tid>>6, l = tid&63;
    int h0   = hist[cls*129 + 2*l];
    int h1   = hist[cls*129 + 2*l+1];
    int h128 = hist[cls*129 + 128];
    int S = h0 + h1;
    for(int off=1; off<64; off<<=1){
      int o = __shfl_down(S, off);
      if(l + off < 64) S += o;
    }
    int ss0 = S + h128;
    int ss1 = S - h0 + h128;
    int cd = -1;
    if(ss0 >= 50) cd = 2*l;
    if(ss1 >= 50) cd = 2*l+1;
    if(l==63 && h128 >= 50) cd = 128;
    for(int off=32; off>0; off>>=1){
      int o = __shfl_down(cd, off);
      cd = o > cd ? o : cd;
    }
    if(l==0) bbinL[cls] = cd;
  }
  __syncthreads();

  // compact both classes in one sweep. Own class: vv-cut (>= -1 is always true
  // when bbin==-1 -- R0's trick). Other class: join as vv=0 filler iff that
  // class has <50 in-strip (reproduces R0's invalid-key list exactly).
  {
    int bb0 = bbinL[0], bb1 = bbinL[1];
    for(int r=0;r<5;r++){
      int pi = tid + r*256;
      if(pi<STRIP){
        uint32_t w  = vvL[pi];
        int own     = (w & 0x80000000u) ? 0 : 1;
        uint32_t vv = w & 0x7FFFFFFFu;
        uint64_t tail = (uint64_t)(16383 - (sub*STRIP + pi));
        int bbo = own ? bb1 : bb0;
        if((int)(vv>>16) >= bbo){
          int pos = atomicAdd(&ncA[own],1);
          cand[own][pos] = ((uint64_t)vv << 14) | tail;
        }
        int bbt = own ? bb0 : bb1;      // other class's bbin
        if(bbt == -1){
          int oth = 1-own;
          int pos = atomicAdd(&ncA[oth],1);
          cand[oth][pos] = tail;        // vv=0 filler, sorts after all valid
        }
      }
    }
  }
  __syncthreads();

  // rank: half-block per class (chunked early-exit, exact for r<50; verbatim
  // R0 rank loop). m>=50 guaranteed (bbin>=0 -> suffix>=50; bbin==-1 -> m=1152).
  {
    int cls = (tid >= 128);
    int lt  = tid & 127;
    int m = ncA[cls];
    const uint64_t* C = cand[cls];
    unsigned long long* dst = key50g + (size_t)img*800 + (size_t)cls*400 + (size_t)sub*50;
    for(int c=lt; c<m; c+=128){
      uint64_t k = C[c];
      int r = 0, j = 0;
      while(j < m){
        int je = j+64 < m ? j+64 : m;
        for(; j<je; j++) r += (C[j] > k);
        if(r >= 50) break;
      }
      if(r < 50) dst[r] = k;            // rank r -> descending sorted list
    }
  }
}

// ---------- K2 (32 blocks): merge 16 strip lists -> top-50/class -> stats ->
// pair-interleaved pack (verbatim R0 baseline kmerge) ------
__global__ __launch_bounds__(256) void kmerge(const float* __restrict__ in,
                                              const unsigned long long* __restrict__ key50g,
                                              float* __restrict__ ts2g,      // [32][600]
                                              float* __restrict__ meanstd){  // [32][10]
#pragma clang fp contract(off)
  int img = blockIdx.x;
  int tid = threadIdx.x;
  __shared__ uint64_t kk[800];
  __shared__ int      tIdx[100];
  __shared__ float    feat[100][5];
  __shared__ float    mv[5], sv[5];

  const uint64_t* kg = (const uint64_t*)key50g + (size_t)img*800;
  for(int c=tid;c<800;c+=256) kk[c] = kg[c];
  __syncthreads();

  // global rank within class via binary search on 8 descending 50-lists (keys unique)
  for(int c=tid;c<800;c+=256){
    uint64_t k = kk[c];
    int cl = (c >= 400);
    int base = cl*400;
    int r = 0;
#pragma unroll
    for(int s=0;s<8;s++){
      const uint64_t* L = &kk[base + s*50];
      int lo=0, hi=50;
      while(lo<hi){ int mid=(lo+hi)>>1; if(L[mid] > k) lo=mid+1; else hi=mid; }
      r += lo;
    }
    if(r < 50) tIdx[cl*50+r] = 16383 - (int)(k & 16383u);
  }
  __syncthreads();

  // train features + stats (math bit-identical)
  if(tid<100){
    int pp = tIdx[tid];
    int i=pp/96, j=pp-i*96;
    const float* px = in + ((size_t)img*NPIX + pp)*3;
    for(int c=0;c<3;c++){
      float ip=clip01_div255(px[c]);
      feat[tid][c]=ip/255.0f;
    }
    feat[tid][3]=((float)i/96.0f)*100.0f;
    feat[tid][4]=((float)j/96.0f)*100.0f;
  }
  __syncthreads();
  if(tid<5){
    float s=0.f;
    for(int r=0;r<100;r++) s=s+feat[r][tid];
    float mu=s/100.0f; mv[tid]=mu;
    float v=0.f;
    for(int r=0;r<100;r++){ float d=feat[r][tid]-mu; float q=d*d; v=v+q; }
    sv[tid]=sqrtf(v/100.0f);
  }
  __syncthreads();
  // pair-interleaved layout: f_k of row r at [pair*12 + 2k + (r&1)], pair=r>>1
  if(tid<100){
    float r0=(feat[tid][0]-mv[0])/sv[0];
    float r1=(feat[tid][1]-mv[1])/sv[1];
    float r2=(feat[tid][2]-mv[2])/sv[2];
    float r3=(feat[tid][3]-mv[3])/sv[3];
    float r4=(feat[tid][4]-mv[4])/sv[4];
    float* dst = ts2g + img*600 + (tid>>1)*12 + (tid&1);
    dst[0]=r0; dst[2]=r1; dst[4]=r2; dst[6]=r3; dst[8]=r4;
  }
  if(tid<5)       meanstd[img*10+tid]=mv[tid];
  else if(tid<10) meanstd[img*10+tid]=sv[tid-5];
}

// ---------- K3: 1152 blocks: 5-NN, packed-pair min/max insertion networks
// (verbatim R0 baseline kknn) ----
__global__ __launch_bounds__(256) void kknn(const float* __restrict__ in,
                                            const float* __restrict__ ts2g,
                                            const float* __restrict__ meanstd,
                                            float* __restrict__ out){
#pragma clang fp contract(off)
  int b     = blockIdx.x;
  int img   = b / 36;
  int chunk = b % 36;
  int tid   = threadIdx.x;

  __shared__ float    mv[5], sv[5];
  __shared__ __attribute__((aligned(16))) float ts2[600];  // pair-interleaved rows
  __shared__ __attribute__((aligned(16))) float pix[768];

  if(tid<150) ((float4*)ts2)[tid] = ((const float4*)(ts2g + img*600))[tid];
  if(tid>=192 && tid<197) mv[tid-192]=meanstd[img*10+(tid-192)];
  if(tid>=224 && tid<229) sv[tid-224]=meanstd[img*10+5+(tid-224)];
  {
    const float4* cb4 = (const float4*)(in + ((size_t)img*NPIX + (size_t)chunk*256)*3);
    if(tid<192) ((float4*)pix)[tid] = cb4[tid];
  }
  __syncthreads();

  // test feature for own pixel (bit-identical math)
  int p = chunk*256+tid;
  int i=p/96, j=p-i*96;
  float ip0=clip01_div255(pix[tid*3+0]);
  float ip1=clip01_div255(pix[tid*3+1]);
  float ip2=clip01_div255(pix[tid*3+2]);
  float t0,t1,t2,t3,t4;
  {
    float f0=ip0/255.0f, f1=ip1/255.0f, f2=ip2/255.0f;
    float f3=((float)i/96.0f)*100.0f, f4=((float)j/96.0f)*100.0f;
    t0=(f0-mv[0])/sv[0]; t1=(f1-mv[1])/sv[1]; t2=(f2-mv[2])/sv[2];
    t3=(f3-mv[3])/sv[3]; t4=(f4-mv[4])/sv[4];
  }

  // fg pairs 0..24 (rows 0..49): packed top-2 via min/max insertion network.
  float a0x=1e30f,a0y=1e30f, a1x=1e30f,a1y=1e30f;
#pragma unroll 5
  for(int pr=0;pr<25;pr++){
    const float* tp = &ts2[pr*12];
    float4 qA = *(const float4*)(tp);    // f0(x,y) f1(x,y)
    float4 qB = *(const float4*)(tp+4);  // f2(x,y) f3(x,y)
    float2 qC = *(const float2*)(tp+8);  // f4(x,y)
    float sx, sy;
    { float dx=t0-qA.x, dy=t0-qA.y; sx=dx*dx; sy=dy*dy; }
    { float dx=t1-qA.z, dy=t1-qA.w; float wx=dx*dx, wy=dy*dy; sx=sx+wx; sy=sy+wy; }
    { float dx=t2-qB.x, dy=t2-qB.y; float wx=dx*dx, wy=dy*dy; sx=sx+wx; sy=sy+wy; }
    { float dx=t3-qB.z, dy=t3-qB.w; float wx=dx*dx, wy=dy*dy; sx=sx+wx; sy=sy+wy; }
    { float dx=t4-qC.x, dy=t4-qC.y; float wx=dx*dx, wy=dy*dy; sx=sx+wx; sy=sy+wy; }
    float tx=fmaxf(a0x,sx), ty=fmaxf(a0y,sy);
    a0x=fminf(a0x,sx);      a0y=fminf(a0y,sy);
    a1x=fminf(a1x,tx);      a1y=fminf(a1y,ty);
  }
  // exact 2nd-smallest of union of the two sorted pairs (bitonic split)
  float a1 = fmaxf(fminf(a0x,a1y), fminf(a1x,a0y));

  // bg pairs 25..49 (rows 50..99): packed top-4 insertion network
  float b0x=1e30f,b0y=1e30f, b1x=1e30f,b1y=1e30f;
  float b2x=1e30f,b2y=1e30f, b3x=1e30f,b3y=1e30f;
#pragma unroll 5
  for(int pr=25;pr<50;pr++){
    const float* tp = &ts2[pr*12];
    float4 qA = *(const float4*)(tp);
    float4 qB = *(const float4*)(tp+4);
    float2 qC = *(const float2*)(tp+8);
    float sx, sy;
    { float dx=t0-qA.x, dy=t0-qA.y; sx=dx*dx; sy=dy*dy; }
    { float dx=t1-qA.z, dy=t1-qA.w; float wx=dx*dx, wy=dy*dy; sx=sx+wx; sy=sy+wy; }
    { float dx=t2-qB.x, dy=t2-qB.y; float wx=dx*dx, wy=dy*dy; sx=sx+wx; sy=sy+wy; }
    { float dx=t3-qB.z, dy=t3-qB.w; float wx=dx*dx, wy=dy*dy; sx=sx+wx; sy=sy+wy; }
    { float dx=t4-qC.x, dy=t4-qC.y; float wx=dx*dx, wy=dy*dy; sx=sx+wx; sy=sy+wy; }
    float u0x=fmaxf(b0x,sx), u0y=fmaxf(b0y,sy);
    b0x=fminf(b0x,sx);       b0y=fminf(b0y,sy);
    float u1x=fmaxf(b1x,u0x), u1y=fmaxf(b1y,u0y);
    b1x=fminf(b1x,u0x);       b1y=fminf(b1y,u0y);
    float u2x=fmaxf(b2x,u1x), u2y=fmaxf(b2y,u1y);
    b2x=fminf(b2x,u1x);       b2y=fminf(b2y,u1y);
    b3x=fminf(b3x,u2x);       b3y=fminf(b3y,u2y);
  }
  // exact 4th-smallest of union of two sorted quads (bitonic lower-half merge)
  float l0=fminf(b0x,b3y), l1=fminf(b1x,b2y), l2=fminf(b2x,b1y), l3=fminf(b3x,b0y);
  float b3 = fmaxf(fmaxf(l0,l1), fmaxf(l2,l3));

  // seg <=> 2nd-smallest fg sqrt-dist <= 4th-smallest bg sqrt-dist (fg wins ties)
  bool seg = sqrtf(a1) <= sqrtf(b3);
  __syncthreads();                       // pix reuse fence
  pix[tid*3+0]=seg?ip0:0.f;
  pix[tid*3+1]=seg?ip1:0.f;
  pix[tid*3+2]=seg?ip2:0.f;
  __syncthreads();
  float4* ob4 = (float4*)(out + ((size_t)img*NPIX + (size_t)chunk*256)*3);
  if(tid<192) ob4[tid] = ((float4*)pix)[tid];
}

extern "C" void kernel_launch(void* const* d_in, const int* in_sizes, int n_in,
                              void* d_out, int out_size, void* d_ws, size_t ws_size,
                              hipStream_t stream) {
  const float* in = (const float*)d_in[0];
  float* out = (float*)d_out;
  float* maxpart = (float*)d_ws;                                          // 2304 B
  unsigned long long* key50g = (unsigned long long*)((char*)d_ws + 2304); // 204800 B
  float* ts2g    = (float*)((char*)d_ws + 207104);                        // 76800 B
  float* meanstd = (float*)((char*)d_ws + 283904);                        // 1280 B

  kmax  <<<192,  256, 0, stream>>>(in, maxpart);
  kscore<<<256,  256, 0, stream>>>(in, maxpart, key50g);
  kmerge<<<32,   256, 0, stream>>>(in, key50g, ts2g, meanstd);
  kknn  <<<1152, 256, 0, stream>>>(in, ts2g, meanstd, out);
}